// Round 8
// baseline (214.091 us; speedup 1.0000x reference)
//
#include <hip/hip_runtime.h>
#include <math.h>

#define BB 4
#define C 64
#define O 64
#define H 128
#define W 128
#define K2 9
#define HW (H*W)
#define NOFF 36

typedef __bf16 bf16;
typedef bf16 bf16x8 __attribute__((ext_vector_type(8)));
typedef float f32x4 __attribute__((ext_vector_type(4)));
typedef unsigned short u16x8 __attribute__((ext_vector_type(8)));

#define BSTR 57                 /* buf row stride dwords; odd -> conflict-free */
#define VAL_BYTES 12288         /* val: [3 taps][64 px][32 ch] bf16 */
#define BUF_BYTES (64*BSTR*4)   /* 14592 */
#define SMEM_BYTES (VAL_BYTES + BUF_BYTES)  /* 26880 -> 6 blocks/CU */
#define WFRAG 18432             /* bf16 per conv-half / group: 9*4*64*8 */
#define NW_TOTAL 73728
#define NBLK 1024

__device__ inline unsigned short f2h_bits(float f) {
  _Float16 h = (_Float16)f;
  return __builtin_bit_cast(unsigned short, h);
}
__device__ inline float h2f(unsigned short u) {
  return (float)__builtin_bit_cast(_Float16, u);
}

// MFMA over a 3-tap K-chunk, role-swapped: this wave owns outputs
// [wv*16, wv*16+16) (A-frag fixed per kk -> 1 global 16B load), and sweeps
// all 64 pixels as 4 B-frag quarters from LDS.
// mfma_f32_16x16x32_bf16 layouts (m89/m120 verified):
//   A: lane holds A[m=lane&15][k=(lane>>4)*8+j]
//   B: lane holds B[k=(lane>>4)*8+j][n=lane&15]
//   D: reg r holds D[m=(lane>>4)*4+r][n=lane&15]
__device__ inline void mfma3(const bf16* __restrict__ wb, int kk0,
                             const bf16* __restrict__ val, int wv, int n16,
                             int q4, int lane, f32x4* acc) {
#pragma unroll
  for (int t = 0; t < 3; ++t) {
    int kk = kk0 + t;
    bf16x8 afr = *(const bf16x8*)(wb + (size_t)((kk * 4 + wv) * 64 + lane) * 8);
#pragma unroll
    for (int qq = 0; qq < 4; ++qq) {
      bf16x8 bfr = *(const bf16x8*)(val + ((t * 64 + qq * 16 + n16) * 32 + q4 * 8));
      acc[qq] = __builtin_amdgcn_mfma_f32_16x16x32_bf16(afr, bfr, acc[qq], 0, 0, 0);
    }
  }
}

// ---------------------------------------------------------------------------
// Single kernel. Phase 1: each block transposes its own 64-px tile of x
// (NCHW fp32 -> NHWC bf16) + 72 weight-swizzle elements. Software grid
// barrier (bar zeroed by a memset graph node; all 1024 blocks co-resident at
// 6 blocks/CU, capacity 1536). Phase 2: fused conv+deform on the same tile.
// ---------------------------------------------------------------------------
__global__ __launch_bounds__(256, 6) void mega(
    const float* __restrict__ x, const float* __restrict__ w_main,
    const float* __restrict__ w_off, const float* __restrict__ w_mask,
    const float* __restrict__ b_off, const float* __restrict__ b_mask,
    unsigned short* xT16, bf16* wfC, bf16* wfM, float* __restrict__ out,
    unsigned int* bar) {
  __shared__ __align__(16) char smem[SMEM_BYTES];
  const int tid = threadIdx.x;
  const int b = blockIdx.x >> 8;
  const int ti = blockIdx.x & 255;

  // ===================== phase 1a: transpose own tile ======================
  {
    float (*tile)[68] = (float (*)[68])smem;  // 64x68 fp32 = 17,408 B
    int p0 = ti * 64;
#pragma unroll
    for (int it = 0; it < 4; ++it) {
      int c = it * 16 + (tid >> 4);
      int p4 = (tid & 15) * 4;
      *(f32x4*)&tile[c][p4] =
          *(const f32x4*)(x + (size_t)(b * C + c) * HW + p0 + p4);
    }
    __syncthreads();
#pragma unroll
    for (int it = 0; it < 2; ++it) {
      int t = it * 256 + tid;
      int p = t >> 3;
      int h8 = t & 7;
      u16x8 o;
#pragma unroll
      for (int j = 0; j < 8; ++j) {
        bf16 v = (bf16)tile[h8 * 8 + j][p];
        o[j] = __builtin_bit_cast(unsigned short, v);
      }
      *(u16x8*)&xT16[(size_t)(b * HW + p0 + p) * C + h8 * 8] = o;
    }
  }
  // ===================== phase 1b: weight swizzle (72/block) ===============
  if (tid < 72) {
    int i = blockIdx.x * 72 + tid;
    int which = (i >= 36864);
    int ii = which ? i - 36864 : i;
    int j = ii & 7;
    int l = (ii >> 3) & 63;
    int rest = ii >> 9;
    int to = rest & 3;
    int kk = (rest >> 2) % 9;
    int ph = (rest >> 2) / 9;
    int m = to * 16 + (l & 15);
    int u = kk * 32 + (l >> 4) * 8 + j;
    int tap = u >> 5;
    int c1 = u & 31;
    if (!which) {
      int c = ph * 32 + c1;
      float v = (m < NOFF) ? w_off[(m * C + c) * K2 + tap]
                : (m < 54) ? w_mask[((m - NOFF) * C + c) * K2 + tap]
                           : 0.f;
      wfC[ii] = (bf16)v;
    } else {
      wfM[ii] = (bf16)w_main[(m * C + ph * 32 + c1) * K2 + tap];
    }
  }

  // ===================== software grid barrier =============================
  __syncthreads();  // drain all waves' phase-1 stores (barrier waits vmcnt)
  if (tid == 0) {
    __threadfence();  // device-scope release: write back L2
    __hip_atomic_fetch_add(bar, 1u, __ATOMIC_ACQ_REL, __HIP_MEMORY_SCOPE_AGENT);
    while (__hip_atomic_load(bar, __ATOMIC_ACQUIRE, __HIP_MEMORY_SCOPE_AGENT) <
           NBLK)
      __builtin_amdgcn_s_sleep(32);
    __threadfence();  // device-scope acquire: invalidate stale L1/L2
  }
  __syncthreads();

  // ===================== phase 2: fused deform on own tile =================
  bf16* val = (bf16*)smem;  // [3][64][32]
  unsigned int (*buf)[BSTR] = (unsigned int (*)[BSTR])(smem + VAL_BYTES);
  float* bufF = (float*)(smem + VAL_BYTES);
  bf16x8* stage16 = (bf16x8*)(smem + VAL_BYTES);  // 816 x 16B = 13,056
  float* valF = (float*)smem;                     // epilogue, stride 68

  const int lane = tid & 63;
  const int wv = tid >> 6;
  const int n16 = lane & 15;
  const int q4 = lane >> 4;
  const int chunk = tid & 3;  // 8-channel 16B chunk
  const int pg = tid >> 2;    // pixel 0..63
  const int h0 = ti >> 1;
  const int w0 = (ti & 1) * 64;
  const bf16* xb = (const bf16*)xT16 + (size_t)b * HW * C;

  bf16x8 zero8;
#pragma unroll
  for (int j = 0; j < 8; ++j) zero8[j] = (bf16)0.f;

  // -------- conv: 2 c-halves x 3 tap-chunks --------
  f32x4 accC[4] = {{0.f,0.f,0.f,0.f},{0.f,0.f,0.f,0.f},
                   {0.f,0.f,0.f,0.f},{0.f,0.f,0.f,0.f}};
#pragma unroll 1
  for (int ph = 0; ph < 2; ++ph) {
    __syncthreads();  // stage/val reuse vs prior readers
#pragma unroll
    for (int it = 0; it < 4; ++it) {  // stage 3x68 window, this half's 32 ch
      int id = it * 256 + tid;
      if (id < 816) {
        int q2 = id & 3;
        int wp = (id >> 2) % 68;
        int r = (id >> 2) / 68;
        int yy = h0 + r - 1;
        int xx = w0 + wp - 1;
        bf16x8 v = zero8;
        if ((unsigned)yy < (unsigned)H && (unsigned)xx < (unsigned)W)
          v = *(const bf16x8*)(xb + (size_t)((yy << 7) + xx) * C + ph * 32 + q2 * 8);
        stage16[id] = v;
      }
    }
    __syncthreads();
#pragma unroll 1
    for (int kc = 0; kc < 3; ++kc) {
      if (kc) __syncthreads();
#pragma unroll
      for (int t = 0; t < 3; ++t) {
        int tap = kc * 3 + t;
        bf16x8 v = stage16[((tap / 3) * 68 + pg + tap % 3) * 4 + chunk];
        *(bf16x8*)(val + ((t * 64 + pg) * 32 + chunk * 8)) = v;
      }
      __syncthreads();
      mfma3(wfC + (size_t)ph * WFRAG, kc * 3, val, wv, n16, q4, lane, accC);
    }
  }
  // conv epilogue: bias + sigmoid -> bufF[p][o] (stage16 readers all done)
  {
#pragma unroll
    for (int qq = 0; qq < 4; ++qq) {
      int p = qq * 16 + n16;
#pragma unroll
      for (int r = 0; r < 4; ++r) {
        int o = wv * 16 + q4 * 4 + r;
        float a = accC[qq][r];
        if (o < NOFF) {
          bufF[p * BSTR + o] = a + b_off[o];
        } else if (o < 54) {
          float s = a + b_mask[o - NOFF];
          bufF[p * BSTR + o] = 1.f / (1.f + __expf(-s));
        }
      }
    }
  }
  __syncthreads();

  // -------- bilinear precompute: 1152 (p,gk) tasks --------
  unsigned int rW0[5], rW1[5], rCo[5];
#pragma unroll
  for (int it = 0; it < 5; ++it) {
    int t = it * 256 + tid;
    if (t < 1152) {
      int p = t & 63;
      int gk = t >> 6;
      int g = gk / 9, tap = gk % 9;
      float offy = bufF[p * BSTR + 2 * gk];
      float offx = bufF[p * BSTR + 2 * gk + 1];
      float m = bufF[p * BSTR + NOFF + gk];
      float py = offy + (float)(h0 + tap / 3 - 1);
      float px = offx + (float)(w0 + p + tap % 3 - 1);
      float y0f = floorf(py), x0f = floorf(px);
      float wy1 = py - y0f, wx1 = px - x0f;
      float wy0 = 1.f - wy1, wx0 = 1.f - wx1;
      int y0 = (int)y0f, x0 = (int)x0f;
      int y1 = y0 + 1, x1 = x0 + 1;
      bool y0ok = (unsigned)y0 < (unsigned)H, y1ok = (unsigned)y1 < (unsigned)H;
      bool x0ok = (unsigned)x0 < (unsigned)W, x1ok = (unsigned)x1 < (unsigned)W;
      float w00 = (y0ok && x0ok) ? wy0 * wx0 * m : 0.f;
      float w01 = (y0ok && x1ok) ? wy0 * wx1 * m : 0.f;
      float w10 = (y1ok && x0ok) ? wy1 * wx0 * m : 0.f;
      float w11 = (y1ok && x1ok) ? wy1 * wx1 * m : 0.f;
      unsigned int y0c = (unsigned)min(max(y0, 0), H - 1);
      unsigned int y1c = (unsigned)min(max(y1, 0), H - 1);
      unsigned int x0c = (unsigned)min(max(x0, 0), W - 1);
      unsigned int x1c = (unsigned)min(max(x1, 0), W - 1);
      rW0[it] = (unsigned)f2h_bits(w00) | ((unsigned)f2h_bits(w01) << 16);
      rW1[it] = (unsigned)f2h_bits(w10) | ((unsigned)f2h_bits(w11) << 16);
      rCo[it] = y0c | (x0c << 8) | (y1c << 16) | (x1c << 24);
    }
  }
  __syncthreads();
#pragma unroll
  for (int it = 0; it < 5; ++it) {
    int t = it * 256 + tid;
    if (t < 1152) {
      int p = t & 63;
      int gk = t >> 6;
      buf[p][2 * gk] = rW0[it];
      buf[p][2 * gk + 1] = rW1[it];
      buf[p][NOFF + gk] = rCo[it];
    }
  }
  __syncthreads();

  // -------- main deform: 2 groups x 3 tap-chunks --------
  f32x4 accM[4] = {{0.f,0.f,0.f,0.f},{0.f,0.f,0.f,0.f},
                   {0.f,0.f,0.f,0.f},{0.f,0.f,0.f,0.f}};
#pragma unroll 1
  for (int g = 0; g < 2; ++g) {
    const bf16* bb = xb + g * 32 + chunk * 8;
#pragma unroll 1
    for (int kc = 0; kc < 3; ++kc) {
      if (g || kc) __syncthreads();  // val reuse vs previous mfma readers
#pragma unroll
      for (int t = 0; t < 3; ++t) {
        int tap = kc * 3 + t;
        int gk = g * 9 + tap;
        unsigned int wab = buf[pg][2 * gk];
        unsigned int wcd = buf[pg][2 * gk + 1];
        unsigned int pk = buf[pg][NOFF + gk];
        float w00 = h2f(wab & 0xffff), w01 = h2f(wab >> 16);
        float w10 = h2f(wcd & 0xffff), w11 = h2f(wcd >> 16);
        int r0 = (int)(pk & 255) << 7;
        int x0 = (int)((pk >> 8) & 255);
        int r1 = (int)((pk >> 16) & 255) << 7;
        int x1 = (int)(pk >> 24);
        bf16x8 v00 = *(const bf16x8*)(bb + (size_t)(r0 + x0) * C);
        bf16x8 v01 = *(const bf16x8*)(bb + (size_t)(r0 + x1) * C);
        bf16x8 v10 = *(const bf16x8*)(bb + (size_t)(r1 + x0) * C);
        bf16x8 v11 = *(const bf16x8*)(bb + (size_t)(r1 + x1) * C);
        bf16x8 res;
#pragma unroll
        for (int j = 0; j < 8; ++j) {
          float v = (float)v00[j] * w00 + (float)v01[j] * w01 +
                    (float)v10[j] * w10 + (float)v11[j] * w11;
          res[j] = (bf16)v;
        }
        *(bf16x8*)(val + ((t * 64 + pg) * 32 + chunk * 8)) = res;
      }
      __syncthreads();
      mfma3(wfM + (size_t)g * WFRAG, kc * 3, val, wv, n16, q4, lane, accM);
    }
  }

  // -------- epilogue: LDS transpose -> coalesced NCHW dwordx4 stores -------
  __syncthreads();  // all mfma readers done before valF overwrites val/buf
  {
#pragma unroll
    for (int qq = 0; qq < 4; ++qq) {
      int p = qq * 16 + n16;
#pragma unroll
      for (int r = 0; r < 4; ++r)
        valF[(wv * 16 + q4 * 4 + r) * 68 + p] = accM[qq][r];
    }
  }
  __syncthreads();
  {
    float* ob = out + (size_t)b * O * HW + (h0 << 7) + w0;
#pragma unroll
    for (int it = 0; it < 4; ++it) {
      int id = it * 256 + tid;
      int o = id >> 4, seg = id & 15;
      f32x4 v = *(f32x4*)&valF[o * 68 + seg * 4];
      *(f32x4*)&ob[(size_t)o * HW + seg * 4] = v;
    }
  }
}

// ---------------------------------------------------------------------------
extern "C" void kernel_launch(void* const* d_in, const int* in_sizes, int n_in,
                              void* d_out, int out_size, void* d_ws,
                              size_t ws_size, hipStream_t stream) {
  const float* x = (const float*)d_in[0];
  const float* w_main = (const float*)d_in[1];
  const float* w_off = (const float*)d_in[2];
  const float* b_off = (const float*)d_in[3];
  const float* w_mask = (const float*)d_in[4];
  const float* b_mask = (const float*)d_in[5];
  float* out = (float*)d_out;

  unsigned short* xT16 = (unsigned short*)d_ws;     // 8,388,608 B
  bf16* wfC = (bf16*)(xT16 + (size_t)BB * HW * C);  // 73,728 B
  bf16* wfM = wfC + 36864;                          // 73,728 B
  unsigned int* bar = (unsigned int*)((char*)d_ws + 8536064);

  hipMemsetAsync(bar, 0, 4, stream);  // zero the grid-barrier counter
  mega<<<NBLK, 256, 0, stream>>>(x, w_main, w_off, w_mask, b_off, b_mask,
                                 xT16, wfC, wfM, out, bar);
}

// Round 9
// 116.946 us; speedup vs baseline: 1.8307x; 1.8307x over previous
//
#include <hip/hip_runtime.h>
#include <math.h>

#define BB 4
#define C 64
#define O 64
#define H 128
#define W 128
#define K2 9
#define HW (H*W)
#define NOFF 36

typedef __bf16 bf16;
typedef bf16 bf16x8 __attribute__((ext_vector_type(8)));
typedef float f32x4 __attribute__((ext_vector_type(4)));
typedef unsigned short u16x8 __attribute__((ext_vector_type(8)));

#define BSTR 55                 /* buf row stride dwords (54 used) */
#define VAL_BYTES 12288         /* val: [3 taps][64 px][32 ch] bf16 */
#define BUF_BYTES (64*BSTR*4)   /* 14080; stage16 (13056) overlays here */
#define SMEM_BYTES (VAL_BYTES + BUF_BYTES)  /* 26368 -> 6 blocks/CU */
#define WFRAG 18432             /* bf16 per conv-half / group: 9*4*64*8 */
#define NW_TOTAL 73728

__device__ inline unsigned short f2h_bits(float f) {
  _Float16 h = (_Float16)f;
  return __builtin_bit_cast(unsigned short, h);
}
__device__ inline float h2f(unsigned short u) {
  return (float)__builtin_bit_cast(_Float16, u);
}

// ---------------------------------------------------------------------------
// K1: NCHW fp32 -> NHWC bf16 transpose (1024 blocks, vectorized) + weight
// swizzle to MFMA a-frag order (blocks 0..287).
//  frag[(ph*9+kk)*4+to][lane][j] = Wrow[m=to*16+(lane&15)][u=kk*32+(lane>>4)*8+j]
//  K order u = tap*32 + c'.  wfC: m<36 w_off, m<54 w_mask, else 0.
// ---------------------------------------------------------------------------
__global__ __launch_bounds__(256) void prep_all(
    const float* __restrict__ x, const float* __restrict__ w_main,
    const float* __restrict__ w_off, const float* __restrict__ w_mask,
    unsigned short* __restrict__ xT16, bf16* __restrict__ wfC,
    bf16* __restrict__ wfM) {
  __shared__ float tile[64][68];
  int tid = threadIdx.x;
  int b = blockIdx.x >> 8;
  int p0 = (blockIdx.x & 255) * 64;
#pragma unroll
  for (int it = 0; it < 4; ++it) {
    int c = it * 16 + (tid >> 4);
    int p4 = (tid & 15) * 4;
    *(f32x4*)&tile[c][p4] =
        *(const f32x4*)(x + (size_t)(b * C + c) * HW + p0 + p4);
  }
  __syncthreads();
#pragma unroll
  for (int it = 0; it < 2; ++it) {
    int t = it * 256 + tid;
    int p = t >> 3;
    int h8 = t & 7;
    u16x8 o;
#pragma unroll
    for (int j = 0; j < 8; ++j) {
      bf16 v = (bf16)tile[h8 * 8 + j][p];
      o[j] = __builtin_bit_cast(unsigned short, v);
    }
    *(u16x8*)&xT16[(size_t)(b * HW + p0 + p) * C + h8 * 8] = o;
  }
  int i = blockIdx.x * 256 + tid;
  if (i < NW_TOTAL) {
    int which = (i >= 36864);
    int ii = which ? i - 36864 : i;
    int j = ii & 7;
    int l = (ii >> 3) & 63;
    int rest = ii >> 9;
    int to = rest & 3;
    int kk = (rest >> 2) % 9;
    int ph = (rest >> 2) / 9;
    int m = to * 16 + (l & 15);
    int u = kk * 32 + (l >> 4) * 8 + j;
    int tap = u >> 5;
    int c1 = u & 31;
    if (!which) {
      int c = ph * 32 + c1;
      float v = (m < NOFF) ? w_off[(m * C + c) * K2 + tap]
                : (m < 54) ? w_mask[((m - NOFF) * C + c) * K2 + tap]
                           : 0.f;
      wfC[ii] = (bf16)v;
    } else {
      wfM[ii] = (bf16)w_main[(m * C + ph * 32 + c1) * K2 + tap];
    }
  }
}

// ---------------------------------------------------------------------------
// K2: fused deform per 64-px tile.
// Conv B-frags are read DIRECTLY from the staged 3x68 pixel window (the
// im2col copy was a layout no-op): B[u=kk*32+c'][p] = stage[kk/3][p+kk%3][c'].
// Main phase: bilinear precompute -> NHWC gather -> val (3-tap chunks) ->
// MFMA.  LDS 26,368 B -> 6 blocks/CU (24 waves) for gather-latency hiding.
// blockIdx swizzle: each XCD (blockIdx%8) works one image -> its 2 MB bf16
// fits the 4 MB XCD L2.
// mfma_f32_16x16x32_bf16 layouts (m89/m120 verified):
//   A: lane holds A[m=lane&15][k=(lane>>4)*8+j]
//   B: lane holds B[k=(lane>>4)*8+j][n=lane&15]
//   D: reg r holds D[m=(lane>>4)*4+r][n=lane&15]
// ---------------------------------------------------------------------------
__global__ __launch_bounds__(256, 6) void fused_deform(
    const bf16* __restrict__ xT, const bf16* __restrict__ wfC,
    const bf16* __restrict__ wfM, const float* __restrict__ b_off,
    const float* __restrict__ b_mask, float* __restrict__ out) {
  __shared__ __align__(16) char smem[SMEM_BYTES];
  bf16* val = (bf16*)smem;                        // [3][64][32]
  unsigned int (*buf)[BSTR] = (unsigned int (*)[BSTR])(smem + VAL_BYTES);
  float* bufF = (float*)(smem + VAL_BYTES);
  bf16x8* stage16 = (bf16x8*)(smem + VAL_BYTES);  // [3][68][4] = 13,056 B
  const bf16* stageb = (const bf16*)(smem + VAL_BYTES);
  float* valF = (float*)smem;                     // epilogue, stride 68

  const int tid = threadIdx.x;
  const int lane = tid & 63;
  const int wv = tid >> 6;
  const int n16 = lane & 15;
  const int q4 = lane >> 4;
  const int chunk = tid & 3;  // 8-channel 16B chunk
  const int pg = tid >> 2;    // pixel 0..63
  const int row = wv * 16 + n16;

  // XCD-aware swizzle: XCD g8 = blockIdx%8 handles image g8>>1 only.
  const int g8 = blockIdx.x & 7;
  const int slot = blockIdx.x >> 3;           // 0..127
  const int b = g8 >> 1;
  const int ti = (g8 & 1) * 128 + slot;       // 0..255
  const int h0 = ti >> 1;
  const int w0 = (ti & 1) * 64;
  const bf16* xb = xT + (size_t)b * HW * C;

  bf16x8 zero8;
#pragma unroll
  for (int j = 0; j < 8; ++j) zero8[j] = (bf16)0.f;

  // ============ conv: 2 c-halves; MFMA straight from stage ============
  f32x4 accC[4] = {{0.f,0.f,0.f,0.f},{0.f,0.f,0.f,0.f},
                   {0.f,0.f,0.f,0.f},{0.f,0.f,0.f,0.f}};
#pragma unroll 1
  for (int ph = 0; ph < 2; ++ph) {
    if (ph) __syncthreads();  // stage reuse vs ph0 MFMA readers
#pragma unroll
    for (int it = 0; it < 4; ++it) {  // stage 3x68 window, this half's 32 ch
      int id = it * 256 + tid;
      if (id < 816) {
        int q2 = id & 3;
        int wp = (id >> 2) % 68;
        int r = (id >> 2) / 68;
        int yy = h0 + r - 1;
        int xx = w0 + wp - 1;
        bf16x8 v = zero8;
        if ((unsigned)yy < (unsigned)H && (unsigned)xx < (unsigned)W)
          v = *(const bf16x8*)(xb + (size_t)((yy << 7) + xx) * C + ph * 32 + q2 * 8);
        stage16[id] = v;
      }
    }
    __syncthreads();
    const bf16* wb = wfC + (size_t)ph * WFRAG;
#pragma unroll
    for (int kk = 0; kk < 9; ++kk) {
      // B[u=kk*32+q4*8+j][row] = x[h0+kk/3-1][w0+row+kk%3-1][ph*32+q4*8+j]
      bf16x8 bfr = *(const bf16x8*)(stageb +
          (size_t)(((kk / 3) * 68 + row + kk % 3) * 4 + q4) * 8);
#pragma unroll
      for (int to = 0; to < 4; ++to) {
        bf16x8 afr = *(const bf16x8*)(wb + (size_t)((kk * 4 + to) * 64 + lane) * 8);
        accC[to] = __builtin_amdgcn_mfma_f32_16x16x32_bf16(afr, bfr, accC[to], 0, 0, 0);
      }
    }
  }
  __syncthreads();  // all stage readers done before bufF overwrites it

  // conv epilogue: bias + sigmoid -> bufF[p][o]
  {
#pragma unroll
    for (int to = 0; to < 4; ++to)
#pragma unroll
      for (int r = 0; r < 4; ++r) {
        int o = to * 16 + q4 * 4 + r;
        float a = accC[to][r];
        if (o < NOFF) {
          bufF[row * BSTR + o] = a + b_off[o];
        } else if (o < 54) {
          float s = a + b_mask[o - NOFF];
          bufF[row * BSTR + o] = 1.f / (1.f + __expf(-s));
        }
      }
  }
  __syncthreads();

  // -------- bilinear precompute: 1152 (p,gk) tasks --------
  unsigned int rW0[5], rW1[5], rCo[5];
#pragma unroll
  for (int it = 0; it < 5; ++it) {
    int t = it * 256 + tid;
    if (t < 1152) {
      int p = t & 63;
      int gk = t >> 6;
      int g = gk / 9, tap = gk % 9;
      float offy = bufF[p * BSTR + 2 * gk];
      float offx = bufF[p * BSTR + 2 * gk + 1];
      float m = bufF[p * BSTR + NOFF + gk];
      float py = offy + (float)(h0 + tap / 3 - 1);
      float px = offx + (float)(w0 + p + tap % 3 - 1);
      float y0f = floorf(py), x0f = floorf(px);
      float wy1 = py - y0f, wx1 = px - x0f;
      float wy0 = 1.f - wy1, wx0 = 1.f - wx1;
      int y0 = (int)y0f, x0 = (int)x0f;
      int y1 = y0 + 1, x1 = x0 + 1;
      bool y0ok = (unsigned)y0 < (unsigned)H, y1ok = (unsigned)y1 < (unsigned)H;
      bool x0ok = (unsigned)x0 < (unsigned)W, x1ok = (unsigned)x1 < (unsigned)W;
      float w00 = (y0ok && x0ok) ? wy0 * wx0 * m : 0.f;
      float w01 = (y0ok && x1ok) ? wy0 * wx1 * m : 0.f;
      float w10 = (y1ok && x0ok) ? wy1 * wx0 * m : 0.f;
      float w11 = (y1ok && x1ok) ? wy1 * wx1 * m : 0.f;
      unsigned int y0c = (unsigned)min(max(y0, 0), H - 1);
      unsigned int y1c = (unsigned)min(max(y1, 0), H - 1);
      unsigned int x0c = (unsigned)min(max(x0, 0), W - 1);
      unsigned int x1c = (unsigned)min(max(x1, 0), W - 1);
      rW0[it] = (unsigned)f2h_bits(w00) | ((unsigned)f2h_bits(w01) << 16);
      rW1[it] = (unsigned)f2h_bits(w10) | ((unsigned)f2h_bits(w11) << 16);
      rCo[it] = y0c | (x0c << 8) | (y1c << 16) | (x1c << 24);
    }
  }
  __syncthreads();
#pragma unroll
  for (int it = 0; it < 5; ++it) {
    int t = it * 256 + tid;
    if (t < 1152) {
      int p = t & 63;
      int gk = t >> 6;
      buf[p][2 * gk] = rW0[it];
      buf[p][2 * gk + 1] = rW1[it];
      buf[p][NOFF + gk] = rCo[it];
    }
  }
  __syncthreads();

  // -------- main deform: 2 groups x 3 tap-chunks --------
  f32x4 accM[4] = {{0.f,0.f,0.f,0.f},{0.f,0.f,0.f,0.f},
                   {0.f,0.f,0.f,0.f},{0.f,0.f,0.f,0.f}};
#pragma unroll 1
  for (int g = 0; g < 2; ++g) {
    const bf16* bb = xb + g * 32 + chunk * 8;
#pragma unroll 1
    for (int kc = 0; kc < 3; ++kc) {
      if (g || kc) __syncthreads();  // val reuse vs previous mfma readers
#pragma unroll
      for (int t = 0; t < 3; ++t) {
        int tap = kc * 3 + t;
        int gk = g * 9 + tap;
        unsigned int wab = buf[pg][2 * gk];
        unsigned int wcd = buf[pg][2 * gk + 1];
        unsigned int pk = buf[pg][NOFF + gk];
        float w00 = h2f(wab & 0xffff), w01 = h2f(wab >> 16);
        float w10 = h2f(wcd & 0xffff), w11 = h2f(wcd >> 16);
        int r0 = (int)(pk & 255) << 7;
        int x0 = (int)((pk >> 8) & 255);
        int r1 = (int)((pk >> 16) & 255) << 7;
        int x1 = (int)(pk >> 24);
        bf16x8 v00 = *(const bf16x8*)(bb + (size_t)(r0 + x0) * C);
        bf16x8 v01 = *(const bf16x8*)(bb + (size_t)(r0 + x1) * C);
        bf16x8 v10 = *(const bf16x8*)(bb + (size_t)(r1 + x0) * C);
        bf16x8 v11 = *(const bf16x8*)(bb + (size_t)(r1 + x1) * C);
        bf16x8 res;
#pragma unroll
        for (int j = 0; j < 8; ++j) {
          float v = (float)v00[j] * w00 + (float)v01[j] * w01 +
                    (float)v10[j] * w10 + (float)v11[j] * w11;
          res[j] = (bf16)v;
        }
        *(bf16x8*)(val + ((t * 64 + pg) * 32 + chunk * 8)) = res;
      }
      __syncthreads();
      const bf16* wb = wfM + (size_t)g * WFRAG;
#pragma unroll
      for (int t = 0; t < 3; ++t) {
        int kk = kc * 3 + t;
        bf16x8 bfr = *(const bf16x8*)(val + ((t * 64 + row) * 32 + q4 * 8));
#pragma unroll
        for (int to = 0; to < 4; ++to) {
          bf16x8 afr = *(const bf16x8*)(wb + (size_t)((kk * 4 + to) * 64 + lane) * 8);
          accM[to] = __builtin_amdgcn_mfma_f32_16x16x32_bf16(afr, bfr, accM[to], 0, 0, 0);
        }
      }
    }
  }

  // -------- epilogue: LDS transpose -> coalesced NCHW dwordx4 stores -------
  __syncthreads();  // all mfma/buf readers done before valF overwrites
  {
#pragma unroll
    for (int to = 0; to < 4; ++to)
#pragma unroll
      for (int r = 0; r < 4; ++r)
        valF[(to * 16 + q4 * 4 + r) * 68 + row] = accM[to][r];
  }
  __syncthreads();
  {
    float* ob = out + (size_t)b * O * HW + (h0 << 7) + w0;
#pragma unroll
    for (int it = 0; it < 4; ++it) {
      int id = it * 256 + tid;
      int o = id >> 4, seg = id & 15;
      f32x4 v = *(f32x4*)&valF[o * 68 + seg * 4];
      *(f32x4*)&ob[(size_t)o * HW + seg * 4] = v;
    }
  }
}

// ---------------------------------------------------------------------------
extern "C" void kernel_launch(void* const* d_in, const int* in_sizes, int n_in,
                              void* d_out, int out_size, void* d_ws,
                              size_t ws_size, hipStream_t stream) {
  const float* x = (const float*)d_in[0];
  const float* w_main = (const float*)d_in[1];
  const float* w_off = (const float*)d_in[2];
  const float* b_off = (const float*)d_in[3];
  const float* w_mask = (const float*)d_in[4];
  const float* b_mask = (const float*)d_in[5];
  float* out = (float*)d_out;

  unsigned short* xT16 = (unsigned short*)d_ws;     // 8,388,608 B
  bf16* wfC = (bf16*)(xT16 + (size_t)BB * HW * C);  // 73,728 B
  bf16* wfM = wfC + 36864;                          // 73,728 B

  prep_all<<<1024, 256, 0, stream>>>(x, w_main, w_off, w_mask, xT16, wfC, wfM);
  fused_deform<<<1024, 256, 0, stream>>>((const bf16*)xT16, wfC, wfM, b_off,
                                         b_mask, out);
}